// Round 7
// baseline (179.670 us; speedup 1.0000x reference)
//
#include <hip/hip_runtime.h>

#define T_LEN 32768
#define B_N   64
#define SEG   64
#define WARM  64
#define NSEG  (T_LEN / SEG)        // 512 segments/sample
#define WPS   (NSEG / 32)          // 16 waves/sample (32 streams per wave)
#define CSKIP (WARM / 32)          // 2 warm chunks
#define NCH   (CSKIP + SEG / 32)   // 4 chunks of 32 steps
#define XROW  33                   // x LDS row stride (banks (m+tt)%32, conflict-free)
#define YROW  33                   // y LDS row stride

typedef __fp16 half2v __attribute__((ext_vector_type(2)));
typedef __fp16 half8  __attribute__((ext_vector_type(8)));
typedef float  f32x16 __attribute__((ext_vector_type(16)));

#define MFMA(a, b, c) __builtin_amdgcn_mfma_f32_32x32x16_f16((a), (b), (c), 0, 0, 0)

#if __has_builtin(__builtin_amdgcn_fdot2)
#define FDOT2(a, b, c) __builtin_amdgcn_fdot2((a), (b), (c), false)
#else
static __device__ __forceinline__ float fdot2_emul(half2v a, half2v b, float c) {
    return fmaf((float)a.x, (float)b.x, fmaf((float)a.y, (float)b.y, c));
}
#define FDOT2(a, b, c) fdot2_emul((a), (b), (c))
#endif

union BU { half2v h2[4]; half8 h8; };

// Row permutation rho (involution): swaps 4..7 <-> 8..11. Chosen so the
// 32x32 MFMA D-layout (row = (reg&3)+8*(reg>>2)+4*kh, col = lane&31) lands
// each lane's gate outputs on jj = 8*kh + reg — exactly the B-fragment
// k-split (lane kh-half holds k = 8*kh + 0..7). So D -> B repack per step
// is 4 cvt_pkrtz with ZERO cross-lane ops. (HW-verified: r4 passed.)
__device__ __forceinline__ int rho(int v) {
    const int q = v >> 2;
    return (q == 1) ? v + 4 : (q == 2) ? v - 4 : v;
}

// r26: PRESSURE CUT. r6 confirmed the 256-VGPR cap + ~65 MB scratch RT is
// genuine allocator pressure (not outlining): ~110 persistent regs + a
// 2-step scheduling window of temps (2 x {c1,d1,d2,ipN,hn} ~ 128) > 256.
// Cuts: (1) h0v8 + per-step pin REPLACED by a one-shot boundary re-pin at
// cc==CSKIP (equivalent: pinned lane's warm trajectory is discarded);
// (2) ipN/hn arrays folded into the nonlinearity loop (write Hd direct);
// (3) sched_barrier(0) per STEP (not pair) — bounds the overlap window to
// one step's temps; the recurrence is serial, cross-step overlap only
// spilled. x prefetch: 1-reg rolling load issued between the MFMAs and the
// transcendental block. Math identical to r4/r6 (passed, absmax 2^-8).
#define GRU_STEP(TT) do {                                                      \
    f32x16 c1;                                                                 \
    _Pragma("unroll")                                                          \
    for (int i = 0; i < 8; ++i) c1[i]     = fmaf(xcur, wihR[i], biasR[i]);     \
    _Pragma("unroll")                                                          \
    for (int i = 0; i < 8; ++i) c1[8 + i] = fmaf(xcur, wihI[i], biasI[i]);     \
    const f32x16 d1 = MFMA(A1u.h8, Bu.h8, c1);                                 \
    const f32x16 d2 = MFMA(A2u.h8, Bu.h8, c2);                                 \
    const float xnx = xr[((TT) + 1 < 32) ? (TT) + 1 : 31];                     \
    _Pragma("unroll")                                                          \
    for (int i = 0; i < 8; ++i) {                                              \
        const float ur  = __builtin_amdgcn_rcpf(1.f + __builtin_amdgcn_exp2f(d1[i]));     \
        const float ui  = __builtin_amdgcn_rcpf(1.f + __builtin_amdgcn_exp2f(d1[8 + i])); \
        const float tno = fmaf(ur, d2[i], fmaf(xcur, wihN[i], bihN[i]));       \
        const float un  = __builtin_amdgcn_rcpf(1.f + __builtin_amdgcn_exp2f(tno));       \
        Hd[i] = fmaf(ui, fmaf(-2.f, un, Hd[i]), un + un);                      \
    }                                                                          \
    _Pragma("unroll")                                                          \
    for (int r = 0; r < 4; ++r)                                                \
        Bu.h2[r] = __builtin_amdgcn_cvt_pkrtz(Hd[2*r], Hd[2*r+1]);             \
    if (doy) ylds[m*YROW + (((TT) + 31) & 31)] = d2[8];                        \
    xcur = xnx;                                                                \
    __builtin_amdgcn_sched_barrier(0);                                         \
} while (0)

// ---- x staging: direct global -> LDS, transient regs only (macro) ----
#define STAGE_X(CC) do {                                                       \
    const int xb_ = xoff + (CC)*32;                                            \
    float v_[16];                                                              \
    if (xb_ >= 0) {                                                            \
        const float4* xp_ = (const float4*)(x + xb_);                          \
        _Pragma("unroll")                                                      \
        for (int j = 0; j < 4; ++j) {                                          \
            const float4 t_ = xp_[j];                                          \
            v_[4*j+0] = t_.x; v_[4*j+1] = t_.y;                                \
            v_[4*j+2] = t_.z; v_[4*j+3] = t_.w;                                \
        }                                                                      \
    } else {                                                                   \
        _Pragma("unroll")                                                      \
        for (int i = 0; i < 16; ++i) {                                         \
            int idx_ = xb_ + i;                                                \
            idx_ = (idx_ < 0) ? 0 : idx_;                                      \
            v_[i] = x[idx_];                                                   \
        }                                                                      \
    }                                                                          \
    _Pragma("unroll")                                                          \
    for (int i = 0; i < 16; ++i) xlds[m*XROW + 16*kh + i] = v_[i];             \
} while (0)

__global__ __launch_bounds__(64, 1) void hyper_gru_kernel(
    const float* __restrict__ x,     const float* __restrict__ c,    const float* __restrict__ h0,
    const float* __restrict__ w1,    const float* __restrict__ b1,
    const float* __restrict__ w2,    const float* __restrict__ b2,
    const float* __restrict__ pihw,  const float* __restrict__ pihb,
    const float* __restrict__ phhw,  const float* __restrict__ phhb,
    const float* __restrict__ pbihw, const float* __restrict__ pbihb,
    const float* __restrict__ pbhhw, const float* __restrict__ pbhhb,
    const float* __restrict__ oww,   const float* __restrict__ owb,
    float* __restrict__ out)
{
    const int blk = blockIdx.x;
    const int b   = blk / WPS;         // sample
    const int w   = blk - b * WPS;     // wave index within sample (16 waves)
    const int ln  = threadIdx.x;
    const int m   = ln & 31;           // A-row / D-col / B-col (stream id)
    const int kh  = ln >> 5;           // k-half (0: k=0..7, 1: k=8..15)

    __shared__ float xlds[32 * XROW];
    __shared__ float ylds[32 * YROW];
    __shared__ float sp[2][48];        // A-row partial sums for bias folds

    // ---- hypernetwork: cond MLP -> a2[8] (uniform; redundant per lane) ----
    float cv[8], a1m[8], a2m[8];
    #pragma unroll
    for (int n = 0; n < 8; ++n) cv[n] = c[b*8 + n];
    #pragma unroll
    for (int mm = 0; mm < 8; ++mm) {
        float sv = b1[mm];
        #pragma unroll
        for (int n = 0; n < 8; ++n) sv = fmaf(cv[n], w1[mm*8 + n], sv);
        a1m[mm] = (sv >= 0.f) ? sv : 0.1f * sv;
    }
    #pragma unroll
    for (int mm = 0; mm < 8; ++mm) {
        float sv = b2[mm];
        #pragma unroll
        for (int k = 0; k < 8; ++k) sv = fmaf(a1m[k], w2[mm*8 + k], sv);
        a2m[mm] = (sv >= 0.f) ? sv : 0.1f * sv;
    }
    auto proj = [&](const float* W, const float* Bv, int row) {
        float sv = Bv[row];
        #pragma unroll
        for (int mm = 0; mm < 8; ++mm) sv = fmaf(a2m[mm], W[row*8 + mm], sv);
        return sv;
    };

    // Scales folded in: r,i: -log2e (sigmoid = rcp(1+exp2(acc)));
    //                   n:   -2log2e (tanh = 2*rcp(1+exp2(acc)) - 1)
    const float SC1 = -1.44269504f, SC2 = -2.88539008f;

    // ---- A fragments (lane owns row m, k = 8*kh + 0..7) ----
    BU A1u, A2u;
    {
        float a1v[8]; float part1 = 0.f;
        const int jw1 = (m < 16) ? rho(m) : 16 + rho(m - 16);   // phh column
        #pragma unroll
        for (int i = 0; i < 8; ++i) {
            const int k = 8*kh + i;
            a1v[i] = SC1 * proj(phhw, phhb, k*48 + jw1);
            part1 += a1v[i];
        }
        __builtin_amdgcn_sched_barrier(0);
        float a2v[8]; float part2 = 0.f;
        if (m < 16) {
            const int jw2 = 32 + rho(m);
            #pragma unroll
            for (int i = 0; i < 8; ++i) {
                const int k = 8*kh + i;
                a2v[i] = SC2 * proj(phhw, phhb, k*48 + jw2);
                part2 += a2v[i];
            }
        } else if (m == 16) {
            #pragma unroll
            for (int i = 0; i < 8; ++i) a2v[i] = oww[8*kh + i];
        } else {
            #pragma unroll
            for (int i = 0; i < 8; ++i) a2v[i] = 0.f;
        }
        __builtin_amdgcn_sched_barrier(0);
        #pragma unroll
        for (int r = 0; r < 4; ++r) {
            A1u.h2[r] = __builtin_amdgcn_cvt_pkrtz(a1v[2*r], a1v[2*r+1]);
            A2u.h2[r] = __builtin_amdgcn_cvt_pkrtz(a2v[2*r], a2v[2*r+1]);
        }
        sp[kh][m] = part1;
        if (m < 16) sp[kh][32 + m] = part2;
    }
    __syncthreads();

    // ---- per-lane constants for jj = 8*kh + i ----
    float wihR[8], wihI[8], wihN[8], biasR[8], biasI[8], bihN[8];
    f32x16 c2;                                  // [biasAN x8, obv, 0...]
    #pragma unroll
    for (int i = 0; i < 8; ++i) {
        const int jj = 8*kh + i;
        const int rr = rho(jj);
        const float sWr = sp[0][rr]      + sp[1][rr];
        const float sWi = sp[0][16 + rr] + sp[1][16 + rr];
        const float sWn = sp[0][32 + rr] + sp[1][32 + rr];
        wihR[i]   = SC1 * proj(pihw, pihb, jj);
        wihI[i]   = SC1 * proj(pihw, pihb, 16 + jj);
        wihN[i]   = SC2 * proj(pihw, pihb, 32 + jj);
        biasR[i]  = SC1 * (proj(pbihw, pbihb, jj) + proj(pbhhw, pbhhb, jj)) - sWr;
        biasI[i]  = SC1 * (proj(pbihw, pbihb, 16 + jj) + proj(pbhhw, pbhhb, 16 + jj)) - sWi;
        bihN[i]   = SC2 * proj(pbihw, pbihb, 32 + jj);
        c2[i]     = SC2 * proj(pbhhw, pbhhb, 32 + jj) - sWn;   // biasAN
        __builtin_amdgcn_sched_barrier(0);
    }
    // packed output weights (for slot-31 direct y) and obv
    half2v owp[4];
    {
        float sumow = 0.f;
        #pragma unroll
        for (int k = 0; k < 16; ++k) sumow += oww[k];
        #pragma unroll
        for (int r = 0; r < 4; ++r)
            owp[r] = __builtin_amdgcn_cvt_pkrtz(oww[8*kh + 2*r], oww[8*kh + 2*r + 1]);
        c2[8] = owb[0] - sumow;                 // obv
        #pragma unroll
        for (int i = 9; i < 16; ++i) c2[i] = 0.f;
    }
    const float obv = c2[8];
    __builtin_amdgcn_sched_barrier(0);

    // ---- state init: H = h+1 (all streams speculate 1; segment 0 gets its
    // exact h0 at the warm->main boundary — equivalent to per-step pinning,
    // since the pinned lane's warm trajectory is discarded anyway) ----
    const bool pinlane = (w == 0) && (m == 0);
    float Hd[8];
    BU Bu;
    #pragma unroll
    for (int i = 0; i < 8; ++i) Hd[i] = 1.f;
    #pragma unroll
    for (int r = 0; r < 4; ++r) Bu.h2[r] = __builtin_amdgcn_cvt_pkrtz(1.f, 1.f);

    const int xoff = b*T_LEN + (32*w + m)*SEG - WARM + 16*kh;  // 16-float aligned when >= 0
    STAGE_X(0);
    __syncthreads();

    // ---- single chunk loop ----
    for (int cc = 0; cc < NCH; ++cc) {
        if (cc == CSKIP) {
            // boundary re-pin: segment 0 starts the main phase exactly at h0
            #pragma unroll
            for (int i = 0; i < 8; ++i) {
                const float hv = h0[b*16 + 8*kh + i] + 1.f;
                Hd[i] = pinlane ? hv : Hd[i];
            }
            #pragma unroll
            for (int r = 0; r < 4; ++r)
                Bu.h2[r] = __builtin_amdgcn_cvt_pkrtz(Hd[2*r], Hd[2*r+1]);
        }
        const bool doy = (cc >= CSKIP) && (kh == 0);
        const float* xr = xlds + m*XROW;
        float xcur = xr[0];
        #pragma unroll
        for (int tt = 0; tt < 32; ++tt) GRU_STEP(tt);

        if (cc >= CSKIP) {
            // slot-31 y from the current (post-chunk) H via packed fdot2 on Bu
            float p = FDOT2(Bu.h2[0], owp[0], 0.f);
            p = FDOT2(Bu.h2[1], owp[1], p);
            p = FDOT2(Bu.h2[2], owp[2], p);
            p = FDOT2(Bu.h2[3], owp[3], p);
            const float p2 = __shfl_xor(p, 32, 64);
            if (kh == 0) ylds[m*YROW + 31] = obv + p + p2;
        }
        __syncthreads();           // ylds complete; xlds reads done

        if (cc >= CSKIP) {
            // write 32 streams x 32 steps; lane: col m, slots 16*kh..+15
            const int tbase = b*T_LEN + (32*w + m)*SEG + (cc - CSKIP)*32 + 16*kh;
            #pragma unroll
            for (int j = 0; j < 4; ++j) {
                float4 o;
                o.x = ylds[m*YROW + 16*kh + 4*j + 0];
                o.y = ylds[m*YROW + 16*kh + 4*j + 1];
                o.z = ylds[m*YROW + 16*kh + 4*j + 2];
                o.w = ylds[m*YROW + 16*kh + 4*j + 3];
                *(float4*)(out + tbase + 4*j) = o;
            }
        }
        if (cc + 1 < NCH) STAGE_X(cc + 1);
        __syncthreads();           // xlds ready for next chunk
    }

    // h_last [B,1,R]: last stream = col 31 of wave WPS-1 (exact f32 state)
    if (w == WPS - 1 && m == 31) {
        #pragma unroll
        for (int i = 0; i < 8; ++i)
            out[B_N * T_LEN + b*16 + 8*kh + i] = Hd[i] - 1.f;
    }
}

extern "C" void kernel_launch(void* const* d_in, const int* in_sizes, int n_in,
                              void* d_out, int out_size, void* d_ws, size_t ws_size,
                              hipStream_t stream) {
    (void)in_sizes; (void)n_in; (void)d_ws; (void)ws_size; (void)out_size;
    hipLaunchKernelGGL(hyper_gru_kernel, dim3(B_N * WPS), dim3(64), 0, stream,
        (const float*)d_in[0],  (const float*)d_in[1],  (const float*)d_in[2],
        (const float*)d_in[3],  (const float*)d_in[4],  (const float*)d_in[5],  (const float*)d_in[6],
        (const float*)d_in[7],  (const float*)d_in[8],  (const float*)d_in[9],  (const float*)d_in[10],
        (const float*)d_in[11], (const float*)d_in[12], (const float*)d_in[13], (const float*)d_in[14],
        (const float*)d_in[15], (const float*)d_in[16],
        (float*)d_out);
}

// Round 8
// 143.828 us; speedup vs baseline: 1.2492x; 1.2492x over previous
//
#include <hip/hip_runtime.h>

#define T_LEN 32768
#define B_N   64
#define SEG   64
#define WARM  64
#define NSEG  (T_LEN / SEG)        // 512 segments/sample
#define SPW   16                   // streams per wave (16x16 MFMA cols)
#define WPS   (NSEG / SPW)         // 32 waves/sample -> grid 2048 (8 blk/CU, 2 waves/SIMD)
#define CSKIP (WARM / 32)          // 2 warm chunks
#define NCH   (CSKIP + SEG / 32)   // 4 chunks of 32 steps
#define XROW  33                   // x LDS row stride (conflict-free)
#define YROW  33                   // y LDS row stride

typedef __fp16 half2v __attribute__((ext_vector_type(2)));
typedef __fp16 half8  __attribute__((ext_vector_type(8)));
typedef float  f32x4  __attribute__((ext_vector_type(4)));

#define MFMA16(a, b, c) __builtin_amdgcn_mfma_f32_16x16x32_f16((a), (b), (c), 0, 0, 0)

union BU { half2v h2[4]; half8 h8; int i4[4]; };

// Row permutation rho (involution): swaps 4..7 <-> 8..11. With the verified
// 16x16 D-layout (col=lane&15, row=(lane>>4)*4+reg), A-rows permuted by rho
// make lane q own H components rho(4q..4q+3):
//   q0:H0-3  q1:H8-11  q2:H4-7  q3:H12-15
// so the B-fragment (lane q' k=8q'+i needs: q0'->H0-7, q1'->H8-15) is
// own-quad + (lane^32)-quad for BOTH q0' and q1' — one shfl_xor(32) pair
// rebuilds B each step, zero other cross-lane ops.
__device__ __forceinline__ int rho(int v) {
    const int qq = v >> 2;
    return (qq == 1) ? v + 4 : (qq == 2) ? v - 4 : v;
}

// r27: SHAPE CHANGE 32x32x16 -> 16x16x32. r4-r7 proved the 32x32 form
// structurally spills: three 16-wide f32 tuples (c1/c2/d1/d2, contiguous
// aligned ranges) + 48 persistent wih/bias regs > 256 arch VGPRs -> ~62 MB
// scratch RT serialized on the chain (~1900 cy/step vs ~300 issue).
// 16x16x32 has K=32 = 16 H-slots + 16 FREE slots: B rows k=16 -> x_t,
// k=17 -> 1 fold the ENTIRE x-projection and all biases into A columns.
// c1/c2/wih/bias cease to exist; D-tuples are 4-wide; C = 0.
// Per step: 4 MFMAs (r,i,n,y-row) + 4-component nonlinearity + B-rebuild
// (2 cvt_pkrtz + 2 shfl_xor + selects). Live set ~50 VGPR -> no spill.
// Segment-parallel correctness (r12) unchanged: WARM=64, boundary re-pin.
#define GRU_STEP(TT) do {                                                      \
    half2v t0_ = __builtin_amdgcn_cvt_pkrtz(Hd[0], Hd[1]);                     \
    half2v t1_ = __builtin_amdgcn_cvt_pkrtz(Hd[2], Hd[3]);                     \
    int p0_, p1_;                                                              \
    __builtin_memcpy(&p0_, &t0_, 4); __builtin_memcpy(&p1_, &t1_, 4);          \
    const int pp0_ = __shfl_xor(p0_, 32, 64);                                  \
    const int pp1_ = __shfl_xor(p1_, 32, 64);                                  \
    half2v tx_ = __builtin_amdgcn_cvt_pkrtz(xcur, 1.0f);                       \
    int xw_; __builtin_memcpy(&xw_, &tx_, 4);                                  \
    BU Bu_;                                                                    \
    Bu_.i4[0] = qlt2 ? p0_ : (isq2 ? xw_ : 0);                                 \
    Bu_.i4[1] = qlt2 ? p1_ : 0;                                                \
    Bu_.i4[2] = qlt2 ? pp0_ : 0;                                               \
    Bu_.i4[3] = qlt2 ? pp1_ : 0;                                               \
    const f32x4 d1 = MFMA16(A1u.h8, Bu_.h8, zero4);                            \
    const f32x4 d2 = MFMA16(A2u.h8, Bu_.h8, zero4);                            \
    const f32x4 d3 = MFMA16(A3u.h8, Bu_.h8, zero4);                            \
    const f32x4 d4 = MFMA16(A4u.h8, Bu_.h8, zero4);                            \
    const float xnx_ = xr[((TT) + 1 < 32) ? (TT) + 1 : 31];                    \
    _Pragma("unroll")                                                          \
    for (int j = 0; j < 4; ++j) {                                              \
        const float ur  = __builtin_amdgcn_rcpf(1.f + __builtin_amdgcn_exp2f(d1[j]));     \
        const float ui  = __builtin_amdgcn_rcpf(1.f + __builtin_amdgcn_exp2f(d2[j]));     \
        const float tno = fmaf(ur, d3[j], fmaf(xcur, wihN4[j], bihN4[j]));     \
        const float un  = __builtin_amdgcn_rcpf(1.f + __builtin_amdgcn_exp2f(tno));       \
        Hd[j] = fmaf(ui, fmaf(-2.f, un, Hd[j]), un + un);                      \
    }                                                                          \
    if (doy) ylds[m16*YROW + (((TT) + 31) & 31)] = d4[0];                      \
    xcur = xnx_;                                                               \
    __builtin_amdgcn_sched_barrier(0);                                         \
} while (0)

// x staging: 16 streams x 32 steps per chunk; lane ln>>2 = row, 8 floats
#define STAGE_X(CC) do {                                                       \
    const int row_ = ln >> 2, cb_ = (ln & 3) * 8;                              \
    const int xb_ = b*T_LEN + (SPW*w + row_)*SEG - WARM + (CC)*32 + cb_;       \
    float v_[8];                                                               \
    if (xb_ >= 0) {                                                            \
        const float4 u0_ = *(const float4*)(x + xb_);                          \
        const float4 u1_ = *(const float4*)(x + xb_ + 4);                      \
        v_[0]=u0_.x; v_[1]=u0_.y; v_[2]=u0_.z; v_[3]=u0_.w;                    \
        v_[4]=u1_.x; v_[5]=u1_.y; v_[6]=u1_.z; v_[7]=u1_.w;                    \
    } else {                                                                   \
        _Pragma("unroll")                                                      \
        for (int i = 0; i < 8; ++i) {                                          \
            int id_ = xb_ + i; id_ = (id_ < 0) ? 0 : id_;                      \
            v_[i] = x[id_];                                                    \
        }                                                                      \
    }                                                                          \
    _Pragma("unroll")                                                          \
    for (int i = 0; i < 8; ++i) xlds[row_*XROW + cb_ + i] = v_[i];             \
} while (0)

__global__ __launch_bounds__(64, 2) void hyper_gru_kernel(
    const float* __restrict__ x,     const float* __restrict__ c,    const float* __restrict__ h0,
    const float* __restrict__ w1,    const float* __restrict__ b1,
    const float* __restrict__ w2,    const float* __restrict__ b2,
    const float* __restrict__ pihw,  const float* __restrict__ pihb,
    const float* __restrict__ phhw,  const float* __restrict__ phhb,
    const float* __restrict__ pbihw, const float* __restrict__ pbihb,
    const float* __restrict__ pbhhw, const float* __restrict__ pbhhb,
    const float* __restrict__ oww,   const float* __restrict__ owb,
    float* __restrict__ out)
{
    const int blk = blockIdx.x;
    const int b   = blk / WPS;         // sample
    const int w   = blk - b * WPS;     // wave index within sample (32 waves)
    const int ln  = threadIdx.x;
    const int m16 = ln & 15;           // A row / B,D col (stream id)
    const int q   = ln >> 4;           // k-group (A/B) and D row-group
    const bool qlt2 = (q < 2);
    const bool isq2 = (q == 2);
    const int pim = rho(m16);          // permuted gate component for A row m16

    __shared__ float xlds[SPW * XROW];
    __shared__ float ylds[SPW * YROW];
    __shared__ float sp[2][3][16];     // k-half partial row sums (r,i,n)

    // ---- hypernetwork: cond MLP -> a2[8] (uniform; redundant per lane) ----
    float cv[8], a1m[8], a2m[8];
    #pragma unroll
    for (int n = 0; n < 8; ++n) cv[n] = c[b*8 + n];
    #pragma unroll
    for (int mm = 0; mm < 8; ++mm) {
        float sv = b1[mm];
        #pragma unroll
        for (int n = 0; n < 8; ++n) sv = fmaf(cv[n], w1[mm*8 + n], sv);
        a1m[mm] = (sv >= 0.f) ? sv : 0.1f * sv;
    }
    #pragma unroll
    for (int mm = 0; mm < 8; ++mm) {
        float sv = b2[mm];
        #pragma unroll
        for (int k = 0; k < 8; ++k) sv = fmaf(a1m[k], w2[mm*8 + k], sv);
        a2m[mm] = (sv >= 0.f) ? sv : 0.1f * sv;
    }
    auto proj = [&](const float* W, const float* Bv, int row) {
        float sv = Bv[row];
        #pragma unroll
        for (int mm = 0; mm < 8; ++mm) sv = fmaf(a2m[mm], W[row*8 + mm], sv);
        return sv;
    };

    // Scales folded in: r,i: -log2e (sigmoid = rcp(1+exp2(acc)));
    //                   n:   -2log2e (tanh = 2*rcp(1+exp2(acc)) - 1)
    const float SC1 = -1.44269504f, SC2 = -2.88539008f;

    // output weight fold
    float sumow = 0.f;
    #pragma unroll
    for (int k = 0; k < 16; ++k) sumow += oww[k];
    const float obv = owb[0] - sumow;

    // ---- A fragments: lane holds A[row=m16, k=8q+i] ----
    // k<16: W_hh columns (rho-permuted rows). k=16: x coeff. k=17: bias. rest 0.
    float A1f[8] = {}, A2f[8] = {}, A3f[8] = {}, A4f[8] = {};
    if (qlt2) {
        float p1 = 0.f, p2 = 0.f, p3 = 0.f;
        #pragma unroll
        for (int i = 0; i < 8; ++i) {
            const int k = 8*q + i;
            A1f[i] = SC1 * proj(phhw, phhb, k*48 + pim);        p1 += A1f[i];
            A2f[i] = SC1 * proj(phhw, phhb, k*48 + 16 + pim);   p2 += A2f[i];
            A3f[i] = SC2 * proj(phhw, phhb, k*48 + 32 + pim);   p3 += A3f[i];
            A4f[i] = (m16 == 0) ? oww[k] : 0.f;
            __builtin_amdgcn_sched_barrier(0);   // bound load-hoisting (anti-spill)
        }
        sp[q][0][m16] = p1;  sp[q][1][m16] = p2;  sp[q][2][m16] = p3;
    }
    __syncthreads();
    if (isq2) {
        const float sWr = sp[0][0][m16] + sp[1][0][m16];
        const float sWi = sp[0][1][m16] + sp[1][1][m16];
        const float sWn = sp[0][2][m16] + sp[1][2][m16];
        A1f[0] = SC1 * proj(pihw, pihb, pim);
        A1f[1] = SC1 * (proj(pbihw, pbihb, pim) + proj(pbhhw, pbhhb, pim)) - sWr;
        A2f[0] = SC1 * proj(pihw, pihb, 16 + pim);
        A2f[1] = SC1 * (proj(pbihw, pbihb, 16 + pim) + proj(pbhhw, pbhhb, 16 + pim)) - sWi;
        A3f[1] = SC2 * proj(pbhhw, pbhhb, 32 + pim) - sWn;     // biasAN (r-multiplied)
        A4f[1] = (m16 == 0) ? obv : 0.f;
        __builtin_amdgcn_sched_barrier(0);
    }
    BU A1u, A2u, A3u, A4u;
    #pragma unroll
    for (int r = 0; r < 4; ++r) {
        A1u.h2[r] = __builtin_amdgcn_cvt_pkrtz(A1f[2*r], A1f[2*r+1]);
        A2u.h2[r] = __builtin_amdgcn_cvt_pkrtz(A2f[2*r], A2f[2*r+1]);
        A3u.h2[r] = __builtin_amdgcn_cvt_pkrtz(A3f[2*r], A3f[2*r+1]);
        A4u.h2[r] = __builtin_amdgcn_cvt_pkrtz(A4f[2*r], A4f[2*r+1]);
    }

    // n-gate x-projection stays on VALU (outside the r-multiplied term);
    // component cj = rho(4q+j) is what this lane's D rows deliver.
    float wihN4[4], bihN4[4], owN4[4];
    #pragma unroll
    for (int j = 0; j < 4; ++j) {
        const int cj = rho(4*q + j);
        wihN4[j] = SC2 * proj(pihw, pihb, 32 + cj);
        bihN4[j] = SC2 * proj(pbihw, pbihb, 32 + cj);
        owN4[j]  = oww[cj];
    }
    __builtin_amdgcn_sched_barrier(0);

    const f32x4 zero4 = {0.f, 0.f, 0.f, 0.f};

    // ---- state: H = h+1; all streams speculate 1; stream 0 re-pinned at
    // the warm->main boundary (equivalent to per-step pinning) ----
    float Hd[4];
    #pragma unroll
    for (int j = 0; j < 4; ++j) Hd[j] = 1.f;

    STAGE_X(0);
    __syncthreads();

    for (int cc = 0; cc < NCH; ++cc) {
        if (cc == CSKIP && w == 0 && m16 == 0) {
            #pragma unroll
            for (int j = 0; j < 4; ++j)
                Hd[j] = h0[b*16 + rho(4*q + j)] + 1.f;
        }
        const bool doy = (cc >= CSKIP) && (ln < 16);
        const float* xr = xlds + m16*XROW;
        float xcur = xr[0];
        #pragma unroll
        for (int tt = 0; tt < 32; ++tt) GRU_STEP(tt);

        if (cc >= CSKIP) {
            // slot-31 y from current H: obv + sum_h ow[h]*H[h] (4 lanes/stream)
            float p = 0.f;
            #pragma unroll
            for (int j = 0; j < 4; ++j) p = fmaf(owN4[j], Hd[j], p);
            p += __shfl_xor(p, 16, 64);
            p += __shfl_xor(p, 32, 64);
            if (ln < 16) ylds[m16*YROW + 31] = obv + p;
        }
        __syncthreads();           // ylds complete; xlds reads done

        if (cc >= CSKIP) {
            const int s_ = ln >> 2, cb_ = (ln & 3) * 8;
            const int tb = b*T_LEN + (SPW*w + s_)*SEG + (cc - CSKIP)*32 + cb_;
            float4 o0, o1;
            o0.x = ylds[s_*YROW + cb_ + 0];
            o0.y = ylds[s_*YROW + cb_ + 1];
            o0.z = ylds[s_*YROW + cb_ + 2];
            o0.w = ylds[s_*YROW + cb_ + 3];
            o1.x = ylds[s_*YROW + cb_ + 4];
            o1.y = ylds[s_*YROW + cb_ + 5];
            o1.z = ylds[s_*YROW + cb_ + 6];
            o1.w = ylds[s_*YROW + cb_ + 7];
            *(float4*)(out + tb)     = o0;
            *(float4*)(out + tb + 4) = o1;
        }
        if (cc + 1 < NCH) STAGE_X(cc + 1);
        __syncthreads();           // xlds ready for next chunk
    }

    // h_last [B,1,R]: last stream = (w=WPS-1, m16=15); exact f32 state
    if (w == WPS - 1 && m16 == 15) {
        #pragma unroll
        for (int j = 0; j < 4; ++j)
            out[B_N * T_LEN + b*16 + rho(4*q + j)] = Hd[j] - 1.f;
    }
}

extern "C" void kernel_launch(void* const* d_in, const int* in_sizes, int n_in,
                              void* d_out, int out_size, void* d_ws, size_t ws_size,
                              hipStream_t stream) {
    (void)in_sizes; (void)n_in; (void)d_ws; (void)ws_size; (void)out_size;
    hipLaunchKernelGGL(hyper_gru_kernel, dim3(B_N * WPS), dim3(64), 0, stream,
        (const float*)d_in[0],  (const float*)d_in[1],  (const float*)d_in[2],
        (const float*)d_in[3],  (const float*)d_in[4],  (const float*)d_in[5],  (const float*)d_in[6],
        (const float*)d_in[7],  (const float*)d_in[8],  (const float*)d_in[9],  (const float*)d_in[10],
        (const float*)d_in[11], (const float*)d_in[12], (const float*)d_in[13], (const float*)d_in[14],
        (const float*)d_in[15], (const float*)d_in[16],
        (float*)d_out);
}